// Round 5
// baseline (20317.316 us; speedup 1.0000x reference)
//
#include <hip/hip_runtime.h>
#include <math.h>

#define Hh   512
#define G3   1536   // 3*H
#define Tlen 512
#define Bsz  64
#define BH   (Bsz*Hh)   // 32768

__device__ __forceinline__ float sigmoid_f(float x) { return 1.0f / (1.0f + expf(-x)); }

// Coherent (IF$-level) scalar store: write-through, bypass L1/L2 dirty state.
__device__ __forceinline__ void store_coh(float* p, float v) {
  asm volatile("global_store_dword %0, %1, off sc0 sc1" :: "v"(p), "v"(v) : "memory");
}

// ---------------------------------------------------------------------------
// GEMM: C[M,N] = A[M,K] @ W[N,K]^T + bias[N]   (fp32, 128x128 tile, 8x8/thread)
// Only used for layer-0 input projection now (K=256).
// ---------------------------------------------------------------------------
__global__ __launch_bounds__(256) void gemm_xg(const float* __restrict__ A,
                                               const float* __restrict__ W,
                                               const float* __restrict__ bias,
                                               float* __restrict__ C,
                                               int M, int N, int K) {
  __shared__ float As[16][132];
  __shared__ float Bs[16][132];
  const int nbm = M >> 7;
  const int bm = blockIdx.x % nbm;
  const int bn = blockIdx.x / nbm;
  const int m0 = bm << 7, n0 = bn << 7;
  const int tid = threadIdx.x;
  const int tx = tid & 15, ty = tid >> 4;

  const int row0 = tid >> 2;
  const int kq0  = (tid & 3) << 2;

  const float* Ap0 = &A[(size_t)(m0 + row0) * K + kq0];
  const float* Ap1 = &A[(size_t)(m0 + row0 + 64) * K + kq0];
  const float* Wp0 = &W[(size_t)(n0 + row0) * K + kq0];
  const float* Wp1 = &W[(size_t)(n0 + row0 + 64) * K + kq0];

  float4 ra0 = *(const float4*)(Ap0);
  float4 ra1 = *(const float4*)(Ap1);
  float4 rb0 = *(const float4*)(Wp0);
  float4 rb1 = *(const float4*)(Wp1);

  float acc[8][8];
#pragma unroll
  for (int r = 0; r < 8; r++)
#pragma unroll
    for (int c = 0; c < 8; c++) acc[r][c] = 0.0f;

  for (int kk = 0; kk < K; kk += 16) {
    As[kq0+0][row0]    = ra0.x; As[kq0+1][row0]    = ra0.y; As[kq0+2][row0]    = ra0.z; As[kq0+3][row0]    = ra0.w;
    As[kq0+0][row0+64] = ra1.x; As[kq0+1][row0+64] = ra1.y; As[kq0+2][row0+64] = ra1.z; As[kq0+3][row0+64] = ra1.w;
    Bs[kq0+0][row0]    = rb0.x; Bs[kq0+1][row0]    = rb0.y; Bs[kq0+2][row0]    = rb0.z; Bs[kq0+3][row0]    = rb0.w;
    Bs[kq0+0][row0+64] = rb1.x; Bs[kq0+1][row0+64] = rb1.y; Bs[kq0+2][row0+64] = rb1.z; Bs[kq0+3][row0+64] = rb1.w;
    __syncthreads();
    const int kn = kk + 16;
    if (kn < K) {
      ra0 = *(const float4*)(Ap0 + kn);
      ra1 = *(const float4*)(Ap1 + kn);
      rb0 = *(const float4*)(Wp0 + kn);
      rb1 = *(const float4*)(Wp1 + kn);
    }
#pragma unroll
    for (int k = 0; k < 16; k++) {
      float4 a0 = *(const float4*)&As[k][ty << 3];
      float4 a1 = *(const float4*)&As[k][(ty << 3) + 4];
      float4 b0 = *(const float4*)&Bs[k][tx << 3];
      float4 b1 = *(const float4*)&Bs[k][(tx << 3) + 4];
      float ar[8] = {a0.x, a0.y, a0.z, a0.w, a1.x, a1.y, a1.z, a1.w};
      float br[8] = {b0.x, b0.y, b0.z, b0.w, b1.x, b1.y, b1.z, b1.w};
#pragma unroll
      for (int r = 0; r < 8; r++)
#pragma unroll
        for (int c = 0; c < 8; c++) acc[r][c] = fmaf(ar[r], br[c], acc[r][c]);
    }
    __syncthreads();
  }
  float bl[8];
#pragma unroll
  for (int c = 0; c < 8; c++) bl[c] = bias[n0 + (tx << 3) + c];
#pragma unroll
  for (int r = 0; r < 8; r++) {
    int m = m0 + (ty << 3) + r;
    float4 o0 = make_float4(acc[r][0] + bl[0], acc[r][1] + bl[1], acc[r][2] + bl[2], acc[r][3] + bl[3]);
    float4 o1 = make_float4(acc[r][4] + bl[4], acc[r][5] + bl[5], acc[r][6] + bl[6], acc[r][7] + bl[7]);
    *(float4*)&C[(size_t)m * N + n0 + (tx << 3)]     = o0;
    *(float4*)&C[(size_t)m * N + n0 + (tx << 3) + 4] = o1;
  }
}

// ---------------------------------------------------------------------------
// Fused 2-layer GRU scan, software-pipelined across layers.
// 512 blocks, 2 per CU (launch_bounds-capped). Role by (blockIdx>>3)&1:
//   role 0: layer-0 scan (identical to proven round-4 kernel; y0 -> ws coherent)
//   role 1: layer-1 scan; per step waits for L0 stamp (y0(t)) + own group h1(t-1),
//           computes BOTH the input projection (W_ih1 frag) and hidden matvec.
// Same fence-free handshake as round 4 (sc0sc1 data stores, relaxed stamps).
// ---------------------------------------------------------------------------
__global__ __launch_bounds__(256, 2) void gru_fused(
    const float* __restrict__ xg0,   // [T,B,3H]  layer-0 input proj (bias folded)
    const float* __restrict__ Whh0,  // [3H,H]
    const float* __restrict__ bhh0,  // [3H]
    const float* __restrict__ Wih1,  // [3H,H]
    const float* __restrict__ bih1,  // [3H]
    const float* __restrict__ Whh1,  // [3H,H]
    const float* __restrict__ bhh1,  // [3H]
    float* __restrict__ y1,          // [T,B,H] output
    float* __restrict__ hn0,         // [B,H]
    float* __restrict__ hn1,         // [B,H]
    float* h0buf, float* h1buf,      // 2 slots of [B][H] each
    float* y0buf,                    // [T,B,H] coherent staging
    int* l0slots, int* l1slots) {    // per role: 8 groups x 32 blocks x 32 ints
  const int tid = threadIdx.x;
  const int jl = tid >> 4;           // 0..15
  const int ks = tid & 15;           // 0..15
  const int bgrp = blockIdx.x & 7;   // batch group (XCD-local heuristic)
  const int rr   = blockIdx.x >> 3;
  const int role = rr & 1;
  const int jgrp = rr >> 1;          // 0..31
  const int j0 = jgrp << 4;
  const int b0 = bgrp << 3;
  const int k0 = ks << 5;

  __shared__ float4 hs4[2][1024];    // two 8x128-float4 tiles (swizzled)

  int* myl0 = l0slots + (bgrp * 32 + jgrp) * 32;
  int* gl0  = l0slots + bgrp * 32 * 32;
  int* myl1 = l1slots + (bgrp * 32 + jgrp) * 32;
  int* gl1  = l1slots + bgrp * 32 * 32;

  int off[8];
#pragma unroll
  for (int q = 0; q < 8; q++) off[q] = (ks * 8 + q) ^ (ks & 7);
  const int fq = tid & 127;
  const int brow = tid >> 7;
  const int fswz = fq ^ ((fq >> 3) & 7);

  if (role == 0) {
    // ================= layer 0 =================
    float4 wv[3][8];
#pragma unroll
    for (int g = 0; g < 3; g++) {
      const float* wp = &Whh0[(size_t)(g * Hh + j0 + jl) * Hh + k0];
#pragma unroll
      for (int q = 0; q < 8; q++) wv[g][q] = *(const float4*)&wp[q * 4];
    }
    float bh[3];
#pragma unroll
    for (int g = 0; g < 3; g++) bh[g] = bhh0[g * Hh + j0 + jl];

    float xr = 0.0f, xz = 0.0f, xn = 0.0f;
    if (ks < 8) {
      const float* xp = &xg0[(size_t)(b0 + ks) * G3 + j0 + jl];
      xr = xp[0]; xz = xp[Hh]; xn = xp[2 * Hh];
    }

    int cur = 0;
    for (int t = 0; t < Tlen; t++) {
      // stage h0 tile (coherent)
      const float4* hsrc = (const float4*)(h0buf + cur * BH) + (size_t)(b0 + brow) * 128 + fq;
      float4 h0, h1, h2, h3;
      {
        const float4* p0 = hsrc;
        const float4* p1 = hsrc + 2 * 128;
        const float4* p2 = hsrc + 4 * 128;
        const float4* p3 = hsrc + 6 * 128;
        asm volatile(
            "global_load_dwordx4 %0, %4, off sc0 sc1\n\t"
            "global_load_dwordx4 %1, %5, off sc0 sc1\n\t"
            "global_load_dwordx4 %2, %6, off sc0 sc1\n\t"
            "global_load_dwordx4 %3, %7, off sc0 sc1\n\t"
            "s_waitcnt vmcnt(0)"
            : "=&v"(h0), "=&v"(h1), "=&v"(h2), "=&v"(h3)
            : "v"(p0), "v"(p1), "v"(p2), "v"(p3)
            : "memory");
      }
      hs4[0][(brow + 0) * 128 + fswz] = h0;
      hs4[0][(brow + 2) * 128 + fswz] = h1;
      hs4[0][(brow + 4) * 128 + fswz] = h2;
      hs4[0][(brow + 6) * 128 + fswz] = h3;
      __syncthreads();

      float acc[3][8];
#pragma unroll
      for (int b = 0; b < 8; b++) {
        float4 hv[8];
#pragma unroll
        for (int q = 0; q < 8; q++) hv[q] = hs4[0][b * 128 + off[q]];
#pragma unroll
        for (int g = 0; g < 3; g++) {
          float s = 0.0f;
#pragma unroll
          for (int q = 0; q < 8; q++) {
            s = fmaf(wv[g][q].x, hv[q].x, s);
            s = fmaf(wv[g][q].y, hv[q].y, s);
            s = fmaf(wv[g][q].z, hv[q].z, s);
            s = fmaf(wv[g][q].w, hv[q].w, s);
          }
          acc[g][b] = s;
        }
      }
#pragma unroll
      for (int d = 1; d < 16; d <<= 1) {
#pragma unroll
        for (int g = 0; g < 3; g++)
#pragma unroll
          for (int b = 0; b < 8; b++) acc[g][b] += __shfl_xor(acc[g][b], d);
      }

      if (ks < 8) {
        int b = b0 + ks;
        int e = j0 + jl;
        float r = sigmoid_f(xr + acc[0][ks] + bh[0]);
        float z = sigmoid_f(xz + acc[1][ks] + bh[1]);
        float n = tanhf(xn + r * (acc[2][ks] + bh[2]));
        int f = e >> 2;
        float4 hp4 = hs4[0][ks * 128 + (f ^ ((f >> 3) & 7))];
        float hp = ((const float*)&hp4)[e & 3];
        float hnew = (1.0f - z) * n + z * hp;
        store_coh(&h0buf[(cur ^ 1) * BH + (size_t)b * Hh + e], hnew);
        store_coh(&y0buf[((size_t)t * Bsz + b) * Hh + e], hnew);
        if (t == Tlen - 1) hn0[(size_t)b * Hh + e] = hnew;
      }

      __syncthreads();   // drain all waves' coherent stores (vmcnt 0 per wave)
      if (tid == 0) {
        __hip_atomic_store(myl0, t + 1, __ATOMIC_RELAXED, __HIP_MEMORY_SCOPE_AGENT);
      }
      if (t == Tlen - 1) break;

      // prefetch xg0[t+1] under the spin
      float nxr = 0.0f, nxz = 0.0f, nxn = 0.0f;
      if (ks < 8) {
        const float* xp = &xg0[((size_t)(t + 1) * Bsz + (b0 + ks)) * G3 + j0 + jl];
        nxr = xp[0]; nxz = xp[Hh]; nxn = xp[2 * Hh];
      }
      if (tid < 64) {
        const int target = t + 1;
        for (;;) {
          int v = (tid < 32)
              ? __hip_atomic_load(gl0 + tid * 32, __ATOMIC_RELAXED, __HIP_MEMORY_SCOPE_AGENT)
              : 0x7FFFFFFF;
          if (!__any(v < target)) break;
          __builtin_amdgcn_s_sleep(1);
        }
      }
      __syncthreads();
      xr = nxr; xz = nxz; xn = nxn;
      cur ^= 1;
    }
  } else {
    // ================= layer 1 =================
    float4 wi[3][8], wh[3][8];
#pragma unroll
    for (int g = 0; g < 3; g++) {
      const float* wip = &Wih1[(size_t)(g * Hh + j0 + jl) * Hh + k0];
      const float* whp = &Whh1[(size_t)(g * Hh + j0 + jl) * Hh + k0];
#pragma unroll
      for (int q = 0; q < 8; q++) {
        wi[g][q] = *(const float4*)&wip[q * 4];
        wh[g][q] = *(const float4*)&whp[q * 4];
      }
    }
    float bi[3], bh[3];
#pragma unroll
    for (int g = 0; g < 3; g++) {
      bi[g] = bih1[g * Hh + j0 + jl];
      bh[g] = bhh1[g * Hh + j0 + jl];
    }

    int cur = 0;
    for (int t = 0; t < Tlen; t++) {
      // wait: y0(t) ready (gl0 >= t+1) AND h1(t-1) ready (gl1 >= t)
      if (tid < 64) {
        const int target = t + 1;
        for (;;) {
          int v;
          if (tid < 32)
            v = __hip_atomic_load(gl0 + tid * 32, __ATOMIC_RELAXED, __HIP_MEMORY_SCOPE_AGENT);
          else
            v = __hip_atomic_load(gl1 + (tid - 32) * 32, __ATOMIC_RELAXED, __HIP_MEMORY_SCOPE_AGENT) + 1;
          if (!__any(v < target)) break;
          __builtin_amdgcn_s_sleep(1);
        }
      }
      __syncthreads();

      // stage y0(t) tile -> hs4[0], h1(t-1) tile -> hs4[1] (coherent)
      const float4* ysrc = (const float4*)(y0buf + (size_t)t * BH) + (size_t)(b0 + brow) * 128 + fq;
      const float4* hsrc = (const float4*)(h1buf + cur * BH) + (size_t)(b0 + brow) * 128 + fq;
      float4 a0, a1, a2, a3, c0, c1, c2, c3;
      {
        const float4* p0 = ysrc;
        const float4* p1 = ysrc + 2 * 128;
        const float4* p2 = ysrc + 4 * 128;
        const float4* p3 = ysrc + 6 * 128;
        const float4* q0 = hsrc;
        const float4* q1 = hsrc + 2 * 128;
        const float4* q2 = hsrc + 4 * 128;
        const float4* q3 = hsrc + 6 * 128;
        asm volatile(
            "global_load_dwordx4 %0, %8, off sc0 sc1\n\t"
            "global_load_dwordx4 %1, %9, off sc0 sc1\n\t"
            "global_load_dwordx4 %2, %10, off sc0 sc1\n\t"
            "global_load_dwordx4 %3, %11, off sc0 sc1\n\t"
            "global_load_dwordx4 %4, %12, off sc0 sc1\n\t"
            "global_load_dwordx4 %5, %13, off sc0 sc1\n\t"
            "global_load_dwordx4 %6, %14, off sc0 sc1\n\t"
            "global_load_dwordx4 %7, %15, off sc0 sc1\n\t"
            "s_waitcnt vmcnt(0)"
            : "=&v"(a0), "=&v"(a1), "=&v"(a2), "=&v"(a3),
              "=&v"(c0), "=&v"(c1), "=&v"(c2), "=&v"(c3)
            : "v"(p0), "v"(p1), "v"(p2), "v"(p3),
              "v"(q0), "v"(q1), "v"(q2), "v"(q3)
            : "memory");
      }
      hs4[0][(brow + 0) * 128 + fswz] = a0;
      hs4[0][(brow + 2) * 128 + fswz] = a1;
      hs4[0][(brow + 4) * 128 + fswz] = a2;
      hs4[0][(brow + 6) * 128 + fswz] = a3;
      hs4[1][(brow + 0) * 128 + fswz] = c0;
      hs4[1][(brow + 2) * 128 + fswz] = c1;
      hs4[1][(brow + 4) * 128 + fswz] = c2;
      hs4[1][(brow + 6) * 128 + fswz] = c3;
      __syncthreads();

      // input-projection dots over y0 tile
      float xga[3][8];
#pragma unroll
      for (int b = 0; b < 8; b++) {
        float4 hv[8];
#pragma unroll
        for (int q = 0; q < 8; q++) hv[q] = hs4[0][b * 128 + off[q]];
#pragma unroll
        for (int g = 0; g < 3; g++) {
          float s = 0.0f;
#pragma unroll
          for (int q = 0; q < 8; q++) {
            s = fmaf(wi[g][q].x, hv[q].x, s);
            s = fmaf(wi[g][q].y, hv[q].y, s);
            s = fmaf(wi[g][q].z, hv[q].z, s);
            s = fmaf(wi[g][q].w, hv[q].w, s);
          }
          xga[g][b] = s;
        }
      }
#pragma unroll
      for (int d = 1; d < 16; d <<= 1) {
#pragma unroll
        for (int g = 0; g < 3; g++)
#pragma unroll
          for (int b = 0; b < 8; b++) xga[g][b] += __shfl_xor(xga[g][b], d);
      }

      // hidden dots over h1 tile
      float acc[3][8];
#pragma unroll
      for (int b = 0; b < 8; b++) {
        float4 hv[8];
#pragma unroll
        for (int q = 0; q < 8; q++) hv[q] = hs4[1][b * 128 + off[q]];
#pragma unroll
        for (int g = 0; g < 3; g++) {
          float s = 0.0f;
#pragma unroll
          for (int q = 0; q < 8; q++) {
            s = fmaf(wh[g][q].x, hv[q].x, s);
            s = fmaf(wh[g][q].y, hv[q].y, s);
            s = fmaf(wh[g][q].z, hv[q].z, s);
            s = fmaf(wh[g][q].w, hv[q].w, s);
          }
          acc[g][b] = s;
        }
      }
#pragma unroll
      for (int d = 1; d < 16; d <<= 1) {
#pragma unroll
        for (int g = 0; g < 3; g++)
#pragma unroll
          for (int b = 0; b < 8; b++) acc[g][b] += __shfl_xor(acc[g][b], d);
      }

      if (ks < 8) {
        int b = b0 + ks;
        int e = j0 + jl;
        float r = sigmoid_f(xga[0][ks] + bi[0] + acc[0][ks] + bh[0]);
        float z = sigmoid_f(xga[1][ks] + bi[1] + acc[1][ks] + bh[1]);
        float n = tanhf(xga[2][ks] + bi[2] + r * (acc[2][ks] + bh[2]));
        int f = e >> 2;
        float4 hp4 = hs4[1][ks * 128 + (f ^ ((f >> 3) & 7))];
        float hp = ((const float*)&hp4)[e & 3];
        float hnew = (1.0f - z) * n + z * hp;
        store_coh(&h1buf[(cur ^ 1) * BH + (size_t)b * Hh + e], hnew);
        y1[((size_t)t * Bsz + b) * Hh + e] = hnew;
        if (t == Tlen - 1) hn1[(size_t)b * Hh + e] = hnew;
      }

      if (t == Tlen - 1) break;
      __syncthreads();
      if (tid == 0) {
        __hip_atomic_store(myl1, t + 1, __ATOMIC_RELAXED, __HIP_MEMORY_SCOPE_AGENT);
      }
      cur ^= 1;
    }
  }
}

// ---------------------------------------------------------------------------
// Launch
// ---------------------------------------------------------------------------
extern "C" void kernel_launch(void* const* d_in, const int* in_sizes, int n_in,
                              void* d_out, int out_size, void* d_ws, size_t ws_size,
                              hipStream_t stream) {
  const float* x     = (const float*)d_in[0];
  const float* Wih0  = (const float*)d_in[1];
  const float* Whh0  = (const float*)d_in[2];
  const float* bih0  = (const float*)d_in[3];
  const float* bhh0  = (const float*)d_in[4];
  const float* Wih1  = (const float*)d_in[5];
  const float* Whh1  = (const float*)d_in[6];
  const float* bih1  = (const float*)d_in[7];
  const float* bhh1  = (const float*)d_in[8];

  float* out = (float*)d_out;
  float* y1   = out;                       // [T,B,H]
  float* hn0  = out + (size_t)Tlen * BH;   // [B,H]
  float* hn1  = hn0 + BH;                  // [B,H]

  // workspace layout (floats):
  //  [0, 16384)        stamps: 2 roles x 8 groups x 32 blocks x 32 ints (64KB)
  //  [16384, +4*BH)    h double buffers (h0: 2 slots, h1: 2 slots)
  //  xg0 buffer        T*B*3H floats (192 MB)
  //  y0 buffer         T*B*H floats (64 MB)
  float* ws     = (float*)d_ws;
  int*   l0slots = (int*)d_ws;
  int*   l1slots = l0slots + 8192;
  float* h0buf  = ws + 16384;
  float* h1buf  = h0buf + 2 * BH;
  float* xg0buf = h1buf + 2 * BH;
  float* y0buf  = xg0buf + (size_t)Tlen * Bsz * G3;

  const int M = Tlen * Bsz;  // 32768

  hipMemsetAsync(l0slots, 0, 2 * 8192 * sizeof(int), stream);
  hipMemsetAsync(h0buf, 0, BH * sizeof(float), stream);   // h0(0) = 0
  hipMemsetAsync(h1buf, 0, BH * sizeof(float), stream);   // h1(0) = 0

  dim3 gemm_grid((M / 128) * (G3 / 128));  // 3072 blocks

  // layer-0 input projection (x @ W_ih0^T + b_ih0)
  gemm_xg<<<gemm_grid, 256, 0, stream>>>(x, Wih0, bih0, xg0buf, M, G3, 256);

  // fused 2-layer pipelined scan
  gru_fused<<<512, 256, 0, stream>>>(xg0buf, Whh0, bhh0, Wih1, bih1, Whh1, bhh1,
                                     y1, hn0, hn1, h0buf, h1buf, y0buf,
                                     l0slots, l1slots);
}